// Round 4
// baseline (805.240 us; speedup 1.0000x reference)
//
#include <hip/hip_runtime.h>
#include <math.h>

#define HW 12544      // 112*112
#define W_IMG 112
#define B_SZ 2

typedef __attribute__((ext_vector_type(8))) short s8v;   // 8 bf16 (4 VGPRs)
typedef __attribute__((ext_vector_type(4))) float f4v;   // MFMA acc

__device__ __forceinline__ void split_bf16(float x, unsigned short& h, unsigned short& l) {
    unsigned u  = __float_as_uint(x);
    unsigned hb = (u + 0x7FFFu + ((u >> 16) & 1u)) >> 16;
    float hf    = __uint_as_float(hb << 16);
    float r     = x - hf;
    unsigned ur = __float_as_uint(r);
    unsigned lb = (ur + 0x7FFFu + ((ur >> 16) & 1u)) >> 16;
    h = (unsigned short)hb; l = (unsigned short)lb;
}

// ---------------------------------------------------------------------------
// Weight split: fp32 [O][K] (optionally two stacked sources, second scaled)
// -> bf16 hi/lo [Mp][Kp], zero padded. 8 conv entries.
// ---------------------------------------------------------------------------
struct WSplitArgs {
    const float* src[8];
    const float* src2[8];
    unsigned short* hi[8];
    unsigned short* lo[8];
    int O1[8]; int O[8]; int K[8]; int Kp[8]; int MpKp[8];
    float scale2[8];
};

__global__ __launch_bounds__(256) void wsplit_k(WSplitArgs a) {
    const int ci  = blockIdx.y;
    const int idx = blockIdx.x * 256 + threadIdx.x;
    if (idx >= a.MpKp[ci]) return;
    const int Kp = a.Kp[ci];
    const int o = idx / Kp, k = idx - o * Kp;
    float v = 0.f;
    if (k < a.K[ci]) {
        if (o < a.O1[ci])
            v = a.src[ci][(size_t)o * a.K[ci] + k];
        else if (o < a.O[ci])
            v = a.src2[ci][(size_t)(o - a.O1[ci]) * a.K[ci] + k] * a.scale2[ci];
    }
    unsigned short h, l;
    split_bf16(v, h, l);
    a.hi[ci][idx] = h; a.lo[ci][idx] = l;
}

// ---------------------------------------------------------------------------
// Transpose + split: fp32 [C][HW] (+bstride per batch) -> bf16 hi/lo [HW][Kp]
// grid (HW/32=392, Kp/32, B), block 256.
// ---------------------------------------------------------------------------
__global__ __launch_bounds__(256) void tsplit_k(
    const float* __restrict__ src, size_t bstride, int C, int Kp,
    unsigned short* __restrict__ hi, unsigned short* __restrict__ lo)
{
    __shared__ __align__(16) float t[32][36];
    const int b   = blockIdx.z;
    const int hw0 = blockIdx.x * 32;
    const int c0  = blockIdx.y * 32;
    const int tid = threadIdx.x;

    {
        const int cl = tid >> 3, hq = (tid & 7) * 4;
        const int c  = c0 + cl;
        float4 v = make_float4(0.f, 0.f, 0.f, 0.f);
        if (c < C)
            v = *(const float4*)(src + (size_t)b * bstride + (size_t)c * HW + hw0 + hq);
        *(float4*)&t[cl][hq] = v;
    }
    __syncthreads();

    const int hl = tid >> 3, cq = (tid & 7) * 4;
    float v0 = t[cq + 0][hl], v1 = t[cq + 1][hl], v2 = t[cq + 2][hl], v3 = t[cq + 3][hl];
    ushort4 h4, l4;
    split_bf16(v0, h4.x, l4.x);
    split_bf16(v1, h4.y, l4.y);
    split_bf16(v2, h4.z, l4.z);
    split_bf16(v3, h4.w, l4.w);
    const size_t row = (size_t)b * HW + hw0 + hl;
    *(ushort4*)(hi + row * Kp + c0 + cq) = h4;
    *(ushort4*)(lo + row * Kp + c0 + cq) = l4;
}

// ---------------------------------------------------------------------------
// Split-bf16 MFMA GEMM, "tall block": one block owns ALL m-tiles for one
// N=64 pixel strip -> B fetched from HBM exactly once per GEMM.
// Waves take m-tiles round-robin (wv, wv+4, ...), up to 6 each (Mtiles<=22).
// Rows [0,OA) -> outA (mode epilogue), rows [OA, OA+OB) -> outB.
// grid (HW/64=196, B), block 256.
// ---------------------------------------------------------------------------
__global__ __launch_bounds__(256) void gemm_k(
    const unsigned short* __restrict__ bt_hi, const unsigned short* __restrict__ bt_lo,
    const unsigned short* __restrict__ w_hi,  const unsigned short* __restrict__ w_lo,
    int Kp, int Mtiles,
    float* __restrict__ outA, int OA, float* __restrict__ outB, int OB,
    int mode,
    const float* __restrict__ res, size_t res_bstride,
    const float* __restrict__ mul, size_t mul_bstride)
{
    const int b     = blockIdx.y;
    const int nbase = blockIdx.x * 64;
    const int tid   = threadIdx.x;
    const int wv    = tid >> 6, lane = tid & 63;
    const int m16   = lane & 15, quad = lane >> 4;

    const int nmt = (Mtiles - wv + 3) >> 2;   // m-tiles for this wave

    const unsigned short* bhp = bt_hi + ((size_t)b * HW + nbase + m16) * Kp + quad * 8;
    const unsigned short* blp = bt_lo + ((size_t)b * HW + nbase + m16) * Kp + quad * 8;
    const unsigned short* whp = w_hi + (size_t)m16 * Kp + quad * 8;
    const unsigned short* wlp = w_lo + (size_t)m16 * Kp + quad * 8;

    f4v acc[6][4];
#pragma unroll
    for (int i = 0; i < 6; ++i)
#pragma unroll
        for (int f = 0; f < 4; ++f) acc[i][f] = (f4v){0.f, 0.f, 0.f, 0.f};

    for (int ks = 0; ks < Kp; ks += 32) {
        s8v bh[4], bl[4];
#pragma unroll
        for (int f = 0; f < 4; ++f) {
            bh[f] = *(const s8v*)(bhp + (size_t)f * 16 * Kp + ks);
            bl[f] = *(const s8v*)(blp + (size_t)f * 16 * Kp + ks);
        }
#pragma unroll
        for (int i = 0; i < 6; ++i) {
            if (i < nmt) {
                const int mt = wv + (i << 2);
                s8v ah = *(const s8v*)(whp + (size_t)mt * 16 * Kp + ks);
                s8v al = *(const s8v*)(wlp + (size_t)mt * 16 * Kp + ks);
#pragma unroll
                for (int f = 0; f < 4; ++f) {
                    acc[i][f] = __builtin_amdgcn_mfma_f32_16x16x32_bf16(ah, bh[f], acc[i][f], 0, 0, 0);
                    acc[i][f] = __builtin_amdgcn_mfma_f32_16x16x32_bf16(al, bh[f], acc[i][f], 0, 0, 0);
                    acc[i][f] = __builtin_amdgcn_mfma_f32_16x16x32_bf16(ah, bl[f], acc[i][f], 0, 0, 0);
                }
            }
        }
    }

#pragma unroll
    for (int i = 0; i < 6; ++i) {
        if (i < nmt) {
            const int mt = wv + (i << 2);
#pragma unroll
            for (int f = 0; f < 4; ++f) {
                const int n = nbase + f * 16 + m16;
#pragma unroll
                for (int r = 0; r < 4; ++r) {
                    const int o = mt * 16 + quad * 4 + r;
                    float v = acc[i][f][r];
                    if (o < OA) {
                        if (mode == 2) {
                            v = tanhf(v) + res[(size_t)b * res_bstride + (size_t)o * HW + n];
                        } else if (mode == 3) {
                            v = (tanhf(v) + res[(size_t)b * res_bstride + (size_t)o * HW + n])
                                * mul[(size_t)b * mul_bstride + (size_t)o * HW + n];
                        }
                        outA[((size_t)b * OA + o) * HW + n] = v;
                    } else if (o - OA < OB) {
                        outB[((size_t)b * OB + (o - OA)) * HW + n] = v;
                    }
                }
            }
        }
    }
}

// ---------------------------------------------------------------------------
// 16x16 block mean-pool 112x112 -> 7x7.  grid (C, B), block 64 (49 active).
// ---------------------------------------------------------------------------
__global__ __launch_bounds__(64) void pool_k(
    const float* __restrict__ ctx, float* __restrict__ pooled, int C)
{
    const int c = blockIdx.x, b = blockIdx.y, t = threadIdx.x;
    if (t >= 49) return;
    const int ph = t / 7, pw = t % 7;
    const float* src = ctx + ((size_t)b * C + c) * HW;
    float sum = 0.f;
    for (int i = 0; i < 16; ++i) {
        const float* row = src + (ph * 16 + i) * W_IMG + pw * 16;
        for (int j = 0; j < 16; ++j) sum += row[j];
    }
    pooled[((size_t)b * C + c) * 49 + t] = sum * (1.0f / 256.0f);
}

// ---------------------------------------------------------------------------
// key[b,o,l] = sum_c wk[o,c] * pooled[b,c,l].  grid (O, B), block 64.
// ---------------------------------------------------------------------------
__global__ __launch_bounds__(64) void keygemm_k(
    const float* __restrict__ pooled, const float* __restrict__ wk,
    float* __restrict__ key, int K, int O)
{
    const int o = blockIdx.x, b = blockIdx.y, l = threadIdx.x;
    if (l >= 49) return;
    float s = 0.f;
    for (int c = 0; c < K; ++c)
        s += wk[(size_t)o * K + c] * pooled[((size_t)b * K + c) * 49 + l];
    key[((size_t)b * O + o) * 49 + l] = s;
}

// ---------------------------------------------------------------------------
// Attention scores + double softmax.  attn layout [b][g][18][HW] (tap-major).
// grid (49, 2, B), block 256.
// ---------------------------------------------------------------------------
__global__ __launch_bounds__(256) void attn_k(
    const float* __restrict__ q, const float* __restrict__ key,
    const float* __restrict__ wp, const float* __restrict__ pb,
    float* __restrict__ attn, int hd)
{
    __shared__ float klds[86 * 52];
    __shared__ float plds[18 * 52];
    __shared__ float pblds[18];

    const int b = blockIdx.z, g = blockIdx.y, tid = threadIdx.x;

    for (int idx = tid; idx < hd * 49; idx += 256) {
        int c = idx / 49, l = idx - c * 49;
        klds[c * 52 + l] = key[((size_t)(b * 2 + g) * hd + c) * 49 + l];
    }
    for (int idx = tid; idx < hd * 3; idx += 256) {
        int c = idx / 3;
        klds[c * 52 + 49 + (idx - c * 3)] = 0.f;
    }
    for (int idx = tid; idx < 18 * 49; idx += 256) {
        int o = idx / 49, l = idx - o * 49;
        plds[o * 52 + l] = wp[o * 49 + l];
    }
    for (int idx = tid; idx < 18 * 3; idx += 256) {
        int o = idx / 3;
        plds[o * 52 + 49 + (idx - o * 3)] = 0.f;
    }
    if (tid < 18) pblds[tid] = pb[tid];
    __syncthreads();

    const int hw = blockIdx.x * 256 + tid;

    float4 s[13];
#pragma unroll
    for (int t = 0; t < 13; ++t) s[t] = make_float4(0.f, 0.f, 0.f, 0.f);

    const float* qp = q + (size_t)(b * 2 + g) * hd * HW + hw;
    for (int c = 0; c < hd; ++c) {
        float qv = qp[(size_t)c * HW];
        const float4* kr = (const float4*)(klds + c * 52);
#pragma unroll
        for (int t = 0; t < 13; ++t) {
            float4 kv = kr[t];
            s[t].x += qv * kv.x; s[t].y += qv * kv.y;
            s[t].z += qv * kv.z; s[t].w += qv * kv.w;
        }
    }

    float e[18];
#pragma unroll
    for (int o = 0; o < 18; ++o) {
        const float4* pr = (const float4*)(plds + o * 52);
        float4 a = make_float4(0.f, 0.f, 0.f, 0.f);
#pragma unroll
        for (int t = 0; t < 13; ++t) {
            float4 pv = pr[t];
            a.x += s[t].x * pv.x; a.y += s[t].y * pv.y;
            a.z += s[t].z * pv.z; a.w += s[t].w * pv.w;
        }
        e[o] = pblds[o] + a.x + a.y + a.z + a.w;
    }

    float* outp = attn + (size_t)(b * 2 + g) * 18 * HW + hw;
#pragma unroll
    for (int half = 0; half < 2; ++half) {
        int base = half * 9;
        float m = e[base];
#pragma unroll
        for (int k = 1; k < 9; ++k) m = fmaxf(m, e[base + k]);
        float sum = 0.f, ex[9];
#pragma unroll
        for (int k = 0; k < 9; ++k) { ex[k] = expf(e[base + k] - m); sum += ex[k]; }
        float inv = 1.0f / sum;
#pragma unroll
        for (int k = 0; k < 9; ++k) outp[(size_t)(base + k) * HW] = ex[k] * inv;
    }
}

// ---------------------------------------------------------------------------
// Dynamic depthwise 3x3 mix, tap-major attn layout. grid (49, C, B), block 256.
// ---------------------------------------------------------------------------
__global__ __launch_bounds__(256) void dyndw_k(
    const float* __restrict__ x, const float* __restrict__ attn,
    float* __restrict__ y, int C, int C_half, int hd, size_t x_bstride)
{
    const int b = blockIdx.z, c = blockIdx.y;
    const int hw = blockIdx.x * 256 + threadIdx.x;
    const int h = hw / W_IMG, w = hw - h * W_IMG;

    const int half = c / C_half;
    const int g = (c - half * C_half) / hd;

    const float* ap = attn + ((size_t)(b * 2 + g) * 18 + half * 9) * HW + hw;
    float a[9];
#pragma unroll
    for (int k = 0; k < 9; ++k) a[k] = ap[(size_t)k * HW];

    const float* xp = x + (size_t)b * x_bstride + (size_t)c * HW;
    float s = 0.f;
#pragma unroll
    for (int i = 0; i < 3; ++i) {
        int hh = h + i - 1;
#pragma unroll
        for (int j = 0; j < 3; ++j) {
            int ww = w + j - 1;
            float v = (hh >= 0 && hh < 112 && ww >= 0 && ww < 112)
                          ? xp[hh * W_IMG + ww] : 0.f;
            s += v * a[i * 3 + j];
        }
    }
    y[((size_t)b * C + c) * HW + hw] = s;
}

// ---------------------------------------------------------------------------
extern "C" void kernel_launch(void* const* d_in, const int* in_sizes, int n_in,
                              void* d_out, int out_size, void* d_ws, size_t ws_size,
                              hipStream_t stream) {
    const float* x      = (const float*)d_in[0];
    const float* pin_w  = (const float*)d_in[1];
    const float* ctx_w  = (const float*)d_in[2];
    const float* ctx1_w = (const float*)d_in[3];
    const float* ctx2_w = (const float*)d_in[4];
    const float* pout_w = (const float*)d_in[5];
    const float* cm0_q  = (const float*)d_in[6];
    const float* cm0_k  = (const float*)d_in[7];
    const float* cm0_p  = (const float*)d_in[8];
    const float* cm0_pb = (const float*)d_in[9];
    const float* cm0_o  = (const float*)d_in[10];
    const float* cm1_q  = (const float*)d_in[11];
    const float* cm1_k  = (const float*)d_in[12];
    const float* cm1_p  = (const float*)d_in[13];
    const float* cm1_pb = (const float*)d_in[14];
    const float* cm1_o  = (const float*)d_in[15];
    const float* cm2_q  = (const float*)d_in[16];
    const float* cm2_k  = (const float*)d_in[17];
    const float* cm2_p  = (const float*)d_in[18];
    const float* cm2_pb = (const float*)d_in[19];
    const float* cm2_o  = (const float*)d_in[20];
    float* out = (float*)d_out;

    float* ws = (float*)d_ws;
    // ---- fp32 region (floats) ----
    float* x_in  = ws;                          // [2,344,HW]
    float* x1p   = ws;                          // [2,172,HW] (after x_in dead)
    float* prod  = ws + 4315136;                // [2,172,HW]
    float* y0    = ws + 8630272;                // [2,344,HW]
    float* y1    = ws + 8630272;                // [2,172,HW]
    float* y2    = ws + 12945408;               // [2,172,HW]
    float* x_dw  = ws + 17260544;               // [2,344,HW]
    float* ctxb  = ws + 25890816;               // [2,86,HW]
    float* ctx1  = ws + 28048384;               // [2,43,HW]
    float* ctx2  = ws + 29127168;               // [2,43,HW]
    float* q0    = ws + 30205952;               // [2,172,HW]
    float* q1    = ws + 30205952;               // [2,86,HW] (after q0 dead)
    float* q2    = ws + 32363520;               // [2,86,HW]
    float* attnb = ws + 34521088;               // [2,2,18,HW]
    float* pooled= ws + 35424256;               // [2,86,49]
    float* keyb  = ws + 35432704;               // [2,172,49]
    // ---- bf16 region (ushorts) ----
    unsigned short* ub = (unsigned short*)(ws + 35449568);
    // conv entries: 0 pin | 1 ctx+q0 | 2 cm0_o | 3 ctx1+q1 | 4 ctx2+q2
    //               5 cm1_o | 6 cm2_o | 7 pout
    static const int WOFF[8] = {0, 45056, 236544, 484352, 539648, 594944, 668672, 742400};
    static const int WO1[8]  = {344, 86, 344, 43, 43, 172, 172, 64};
    static const int WO[8]   = {344, 258, 344, 129, 129, 172, 172, 64};
    static const int WK[8]   = {64, 344, 344, 172, 172, 172, 172, 172};
    static const int WKP[8]  = {64, 352, 352, 192, 192, 192, 192, 192};
    static const int WMP[8]  = {352, 272, 352, 144, 144, 192, 192, 64};
    // X_t planes
    unsigned short* xt_hi   = ub + 766976;      // [2,HW,64]
    unsigned short* xt_lo   = ub + 2372608;
    unsigned short* xint_hi = ub + 3978240;     // [2,HW,352] (pool A)
    unsigned short* xint_lo = ub + 12809216;
    unsigned short* x1t_hi  = ub + 3978240;     // [2,HW,192] (pool A reuse)
    unsigned short* x1t_lo  = ub + 8795136;
    unsigned short* x2t_hi  = ub + 13612032;
    unsigned short* x2t_lo  = ub + 18428928;
    unsigned short* yt_hi   = ub + 23245824;    // [2,HW,352] (pool B)
    unsigned short* yt_lo   = ub + 32076800;
    unsigned short* y1t_hi  = ub + 23245824;    // [2,HW,192] (pool B reuse)
    unsigned short* y1t_lo  = ub + 28062720;
    unsigned short* y2t_hi  = ub + 32879616;
    unsigned short* y2t_lo  = ub + 37696512;
    unsigned short* pt_hi   = ub + 42513408;    // [2,HW,192]
    unsigned short* pt_lo   = ub + 47330304;

    const float sc0 = 1.0f / sqrtf(86.0f);
    const float sc1 = 1.0f / sqrtf(43.0f);
    const size_t BS344 = (size_t)344 * HW, BS172 = (size_t)172 * HW, BS64 = (size_t)64 * HW;

    // ---- 0. split/concat all weights (q-scales folded into weights) ----
    WSplitArgs wa;
    const float* wsrc1[8] = {pin_w, ctx_w, cm0_o, ctx1_w, ctx2_w, cm1_o, cm2_o, pout_w};
    const float* wsrc2[8] = {nullptr, cm0_q, nullptr, cm1_q, cm2_q, nullptr, nullptr, nullptr};
    const float wsc2[8]   = {1.f, sc0, 1.f, sc1, sc1, 1.f, 1.f, 1.f};
    for (int i = 0; i < 8; ++i) {
        wa.src[i] = wsrc1[i]; wa.src2[i] = wsrc2[i];
        wa.hi[i]  = ub + WOFF[i];
        wa.lo[i]  = ub + WOFF[i] + WMP[i] * WKP[i];
        wa.O1[i] = WO1[i]; wa.O[i] = WO[i]; wa.K[i] = WK[i]; wa.Kp[i] = WKP[i];
        wa.MpKp[i] = WMP[i] * WKP[i];
        wa.scale2[i] = wsc2[i];
    }
    wsplit_k<<<dim3(484, 8), 256, 0, stream>>>(wa);

#define TSPLIT(SRC, BSTR, C, KP, HI, LO)                                        \
    tsplit_k<<<dim3(392, (KP) / 32, B_SZ), 256, 0, stream>>>(SRC, BSTR, C, KP, HI, LO)
#define GEMM(CI, BH, BL, OUTA, OUTB, OB, MODE, RES, RB, MUL, MB)                \
    gemm_k<<<dim3(196, B_SZ), 256, 0, stream>>>(                                \
        BH, BL, ub + WOFF[CI], ub + WOFF[CI] + WMP[CI] * WKP[CI],               \
        WKP[CI], WMP[CI] / 16, OUTA, WO1[CI], OUTB, OB, MODE, RES, RB, MUL, MB)

    // ---- pin: x_in = pin_w @ x ----
    TSPLIT(x, BS64, 64, 64, xt_hi, xt_lo);
    GEMM(0, xt_hi, xt_lo, x_in, nullptr, 0, 0, nullptr, 0, nullptr, 0);
    TSPLIT(x_in, BS344, 344, 352, xint_hi, xint_lo);

    // ---- contmix0: fused ctx_dw + q0 GEMM ----
    GEMM(1, xint_hi, xint_lo, ctxb, q0, 172, 0, nullptr, 0, nullptr, 0);
    pool_k<<<dim3(86, B_SZ), dim3(64), 0, stream>>>(ctxb, pooled, 86);
    keygemm_k<<<dim3(172, B_SZ), dim3(64), 0, stream>>>(pooled, cm0_k, keyb, 86, 172);
    attn_k<<<dim3(49, 2, B_SZ), dim3(256), 0, stream>>>(q0, keyb, cm0_p, cm0_pb, attnb, 86);
    dyndw_k<<<dim3(49, 344, B_SZ), dim3(256), 0, stream>>>(x_in, attnb, y0, 344, 172, 86, BS344);
    TSPLIT(y0, BS344, 344, 352, yt_hi, yt_lo);
    GEMM(2, yt_hi, yt_lo, x_dw, nullptr, 0, 0, nullptr, 0, nullptr, 0);

    // ---- transpose halves of x_dw ----
    TSPLIT(x_dw, BS344, 172, 192, x1t_hi, x1t_lo);
    TSPLIT(x_dw + BS172, BS344, 172, 192, x2t_hi, x2t_lo);

    // ---- contmix1 on x1 ----
    GEMM(3, x1t_hi, x1t_lo, ctx1, q1, 86, 0, nullptr, 0, nullptr, 0);
    pool_k<<<dim3(43, B_SZ), dim3(64), 0, stream>>>(ctx1, pooled, 43);
    keygemm_k<<<dim3(86, B_SZ), dim3(64), 0, stream>>>(pooled, cm1_k, keyb, 43, 86);
    attn_k<<<dim3(49, 2, B_SZ), dim3(256), 0, stream>>>(q1, keyb, cm1_p, cm1_pb, attnb, 43);
    dyndw_k<<<dim3(49, 172, B_SZ), dim3(256), 0, stream>>>(x_dw, attnb, y1, 172, 86, 43, BS344);
    TSPLIT(y1, BS172, 172, 192, y1t_hi, y1t_lo);
    GEMM(5, y1t_hi, y1t_lo, x1p, nullptr, 0, 2, x_dw, BS344, nullptr, 0);

    // ---- contmix2 on x2 ----
    GEMM(4, x2t_hi, x2t_lo, ctx2, q2, 86, 0, nullptr, 0, nullptr, 0);
    pool_k<<<dim3(43, B_SZ), dim3(64), 0, stream>>>(ctx2, pooled, 43);
    keygemm_k<<<dim3(86, B_SZ), dim3(64), 0, stream>>>(pooled, cm2_k, keyb, 43, 86);
    attn_k<<<dim3(49, 2, B_SZ), dim3(256), 0, stream>>>(q2, keyb, cm2_p, cm2_pb, attnb, 43);
    dyndw_k<<<dim3(49, 172, B_SZ), dim3(256), 0, stream>>>(x_dw + BS172, attnb, y2, 172, 86, 43, BS344);
    TSPLIT(y2, BS172, 172, 192, y2t_hi, y2t_lo);
    GEMM(6, y2t_hi, y2t_lo, prod, nullptr, 0, 3, x_dw + BS172, BS344, x1p, BS172);

    // ---- pout ----
    TSPLIT(prod, BS172, 172, 192, pt_hi, pt_lo);
    GEMM(7, pt_hi, pt_lo, out, nullptr, 0, 0, nullptr, 0, nullptr, 0);

#undef TSPLIT
#undef GEMM
}

// Round 5
// 675.483 us; speedup vs baseline: 1.1921x; 1.1921x over previous
//
#include <hip/hip_runtime.h>
#include <math.h>

#define HW 12544      // 112*112
#define W_IMG 112
#define B_SZ 2

typedef __attribute__((ext_vector_type(8))) short s8v;   // 8 bf16 (4 VGPRs)
typedef __attribute__((ext_vector_type(4))) float f4v;   // MFMA acc

__device__ __forceinline__ void split_bf16(float x, unsigned short& h, unsigned short& l) {
    unsigned u  = __float_as_uint(x);
    unsigned hb = (u + 0x7FFFu + ((u >> 16) & 1u)) >> 16;
    float hf    = __uint_as_float(hb << 16);
    float r     = x - hf;
    unsigned ur = __float_as_uint(r);
    unsigned lb = (ur + 0x7FFFu + ((ur >> 16) & 1u)) >> 16;
    h = (unsigned short)hb; l = (unsigned short)lb;
}

// ---------------------------------------------------------------------------
// Weight split: fp32 [O][K] (optionally two stacked sources, second scaled)
// -> bf16 hi/lo [Mp][Kp], zero padded. 8 conv entries.
// ---------------------------------------------------------------------------
struct WSplitArgs {
    const float* src[8];
    const float* src2[8];
    unsigned short* hi[8];
    unsigned short* lo[8];
    int O1[8]; int O[8]; int K[8]; int Kp[8]; int MpKp[8];
    float scale2[8];
};

__global__ __launch_bounds__(256) void wsplit_k(WSplitArgs a) {
    const int ci  = blockIdx.y;
    const int idx = blockIdx.x * 256 + threadIdx.x;
    if (idx >= a.MpKp[ci]) return;
    const int Kp = a.Kp[ci];
    const int o = idx / Kp, k = idx - o * Kp;
    float v = 0.f;
    if (k < a.K[ci]) {
        if (o < a.O1[ci])
            v = a.src[ci][(size_t)o * a.K[ci] + k];
        else if (o < a.O[ci])
            v = a.src2[ci][(size_t)(o - a.O1[ci]) * a.K[ci] + k] * a.scale2[ci];
    }
    unsigned short h, l;
    split_bf16(v, h, l);
    a.hi[ci][idx] = h; a.lo[ci][idx] = l;
}

// ---------------------------------------------------------------------------
// Transpose + split: fp32 [C][HW] (+bstride per batch) -> bf16 hi/lo [HW][Kp]
// grid (HW/32=392, Kp/32, B), block 256.
// ---------------------------------------------------------------------------
__global__ __launch_bounds__(256) void tsplit_k(
    const float* __restrict__ src, size_t bstride, int C, int Kp,
    unsigned short* __restrict__ hi, unsigned short* __restrict__ lo)
{
    __shared__ __align__(16) float t[32][36];
    const int b   = blockIdx.z;
    const int hw0 = blockIdx.x * 32;
    const int c0  = blockIdx.y * 32;
    const int tid = threadIdx.x;

    {
        const int cl = tid >> 3, hq = (tid & 7) * 4;
        const int c  = c0 + cl;
        float4 v = make_float4(0.f, 0.f, 0.f, 0.f);
        if (c < C)
            v = *(const float4*)(src + (size_t)b * bstride + (size_t)c * HW + hw0 + hq);
        *(float4*)&t[cl][hq] = v;
    }
    __syncthreads();

    const int hl = tid >> 3, cq = (tid & 7) * 4;
    float v0 = t[cq + 0][hl], v1 = t[cq + 1][hl], v2 = t[cq + 2][hl], v3 = t[cq + 3][hl];
    ushort4 h4, l4;
    split_bf16(v0, h4.x, l4.x);
    split_bf16(v1, h4.y, l4.y);
    split_bf16(v2, h4.z, l4.z);
    split_bf16(v3, h4.w, l4.w);
    const size_t row = (size_t)b * HW + hw0 + hl;
    *(ushort4*)(hi + row * Kp + c0 + cq) = h4;
    *(ushort4*)(lo + row * Kp + c0 + cq) = l4;
}

// ---------------------------------------------------------------------------
// Split-bf16 MFMA GEMM, M-x-N grid with XCD-aware swizzle.
// Wave: M=32 (2 mtiles) x N=64; block = 4 waves -> tile M32 x N256.
// Swizzle: all m-blocks of one n-strip -> same XCD (round-robin dispatch
// assumption), so the B strip is fetched into that XCD's L2 once.
// Rows [0,OA) -> outA (mode epilogue), rows [OA,OA+OB) -> outB.
// grid (per_m*56, B), block 256.  ns = (t/per_m)*8 + (bx&7), exit if ns>=49.
// ---------------------------------------------------------------------------
__global__ __launch_bounds__(256) void gemm_k(
    const unsigned short* __restrict__ bt_hi, const unsigned short* __restrict__ bt_lo,
    const unsigned short* __restrict__ w_hi,  const unsigned short* __restrict__ w_lo,
    int Kp, int per_m,
    float* __restrict__ outA, int OA, float* __restrict__ outB, int OB,
    int mode,
    const float* __restrict__ res, size_t res_bstride,
    const float* __restrict__ mul, size_t mul_bstride)
{
    const int b   = blockIdx.y;
    const int bx  = blockIdx.x;
    const int xcd = bx & 7, t = bx >> 3;
    const int m   = t % per_m;
    const int ns  = (t / per_m) * 8 + xcd;
    if (ns >= 49) return;

    const int tid  = threadIdx.x;
    const int wv   = tid >> 6, lane = tid & 63;
    const int m16  = lane & 15, quad = lane >> 4;
    const int mbase = m * 32;
    const int nbase = ns * 256 + wv * 64;

    const unsigned short* wh0 = w_hi + (size_t)(mbase + m16) * Kp + quad * 8;
    const unsigned short* wl0 = w_lo + (size_t)(mbase + m16) * Kp + quad * 8;
    const unsigned short* wh1 = wh0 + (size_t)16 * Kp;
    const unsigned short* wl1 = wl0 + (size_t)16 * Kp;

    const unsigned short* bh[4];
    const unsigned short* bl[4];
#pragma unroll
    for (int f = 0; f < 4; ++f) {
        size_t roff = ((size_t)b * HW + nbase + f * 16 + m16) * Kp + quad * 8;
        bh[f] = bt_hi + roff; bl[f] = bt_lo + roff;
    }

    f4v acc0[4], acc1[4];
#pragma unroll
    for (int f = 0; f < 4; ++f) {
        acc0[f] = (f4v){0.f, 0.f, 0.f, 0.f};
        acc1[f] = (f4v){0.f, 0.f, 0.f, 0.f};
    }

    for (int ks = 0; ks < Kp; ks += 32) {
        s8v ah0 = *(const s8v*)(wh0 + ks);
        s8v al0 = *(const s8v*)(wl0 + ks);
        s8v ah1 = *(const s8v*)(wh1 + ks);
        s8v al1 = *(const s8v*)(wl1 + ks);
#pragma unroll
        for (int f = 0; f < 4; ++f) {
            s8v bhf = *(const s8v*)(bh[f] + ks);
            s8v blf = *(const s8v*)(bl[f] + ks);
            acc0[f] = __builtin_amdgcn_mfma_f32_16x16x32_bf16(ah0, bhf, acc0[f], 0, 0, 0);
            acc0[f] = __builtin_amdgcn_mfma_f32_16x16x32_bf16(al0, bhf, acc0[f], 0, 0, 0);
            acc0[f] = __builtin_amdgcn_mfma_f32_16x16x32_bf16(ah0, blf, acc0[f], 0, 0, 0);
            acc1[f] = __builtin_amdgcn_mfma_f32_16x16x32_bf16(ah1, bhf, acc1[f], 0, 0, 0);
            acc1[f] = __builtin_amdgcn_mfma_f32_16x16x32_bf16(al1, bhf, acc1[f], 0, 0, 0);
            acc1[f] = __builtin_amdgcn_mfma_f32_16x16x32_bf16(ah1, blf, acc1[f], 0, 0, 0);
        }
    }

#pragma unroll
    for (int mp = 0; mp < 2; ++mp) {
#pragma unroll
        for (int f = 0; f < 4; ++f) {
            const int n = nbase + f * 16 + m16;
#pragma unroll
            for (int r = 0; r < 4; ++r) {
                const int o = mbase + mp * 16 + quad * 4 + r;
                float v = mp ? acc1[f][r] : acc0[f][r];
                if (o < OA) {
                    if (mode == 2) {
                        v = tanhf(v) + res[(size_t)b * res_bstride + (size_t)o * HW + n];
                    } else if (mode == 3) {
                        v = (tanhf(v) + res[(size_t)b * res_bstride + (size_t)o * HW + n])
                            * mul[(size_t)b * mul_bstride + (size_t)o * HW + n];
                    }
                    outA[((size_t)b * OA + o) * HW + n] = v;
                } else if (o - OA < OB) {
                    outB[((size_t)b * OB + (o - OA)) * HW + n] = v;
                }
            }
        }
    }
}

// ---------------------------------------------------------------------------
// 16x16 block mean-pool 112x112 -> 7x7.  grid (C, B), block 64 (49 active).
// ---------------------------------------------------------------------------
__global__ __launch_bounds__(64) void pool_k(
    const float* __restrict__ ctx, float* __restrict__ pooled, int C)
{
    const int c = blockIdx.x, b = blockIdx.y, t = threadIdx.x;
    if (t >= 49) return;
    const int ph = t / 7, pw = t % 7;
    const float* src = ctx + ((size_t)b * C + c) * HW;
    float sum = 0.f;
    for (int i = 0; i < 16; ++i) {
        const float* row = src + (ph * 16 + i) * W_IMG + pw * 16;
        for (int j = 0; j < 16; ++j) sum += row[j];
    }
    pooled[((size_t)b * C + c) * 49 + t] = sum * (1.0f / 256.0f);
}

// ---------------------------------------------------------------------------
// key[b,o,l] = sum_c wk[o,c] * pooled[b,c,l].  grid (O, B), block 64.
// ---------------------------------------------------------------------------
__global__ __launch_bounds__(64) void keygemm_k(
    const float* __restrict__ pooled, const float* __restrict__ wk,
    float* __restrict__ key, int K, int O)
{
    const int o = blockIdx.x, b = blockIdx.y, l = threadIdx.x;
    if (l >= 49) return;
    float s = 0.f;
    for (int c = 0; c < K; ++c)
        s += wk[(size_t)o * K + c] * pooled[((size_t)b * K + c) * 49 + l];
    key[((size_t)b * O + o) * 49 + l] = s;
}

// ---------------------------------------------------------------------------
// Attention scores + double softmax.  attn layout [b][g][18][HW] (tap-major).
// grid (49, 2, B), block 256.
// ---------------------------------------------------------------------------
__global__ __launch_bounds__(256) void attn_k(
    const float* __restrict__ q, const float* __restrict__ key,
    const float* __restrict__ wp, const float* __restrict__ pb,
    float* __restrict__ attn, int hd)
{
    __shared__ float klds[86 * 52];
    __shared__ float plds[18 * 52];
    __shared__ float pblds[18];

    const int b = blockIdx.z, g = blockIdx.y, tid = threadIdx.x;

    for (int idx = tid; idx < hd * 49; idx += 256) {
        int c = idx / 49, l = idx - c * 49;
        klds[c * 52 + l] = key[((size_t)(b * 2 + g) * hd + c) * 49 + l];
    }
    for (int idx = tid; idx < hd * 3; idx += 256) {
        int c = idx / 3;
        klds[c * 52 + 49 + (idx - c * 3)] = 0.f;
    }
    for (int idx = tid; idx < 18 * 49; idx += 256) {
        int o = idx / 49, l = idx - o * 49;
        plds[o * 52 + l] = wp[o * 49 + l];
    }
    for (int idx = tid; idx < 18 * 3; idx += 256) {
        int o = idx / 3;
        plds[o * 52 + 49 + (idx - o * 3)] = 0.f;
    }
    if (tid < 18) pblds[tid] = pb[tid];
    __syncthreads();

    const int hw = blockIdx.x * 256 + tid;

    float4 s[13];
#pragma unroll
    for (int t = 0; t < 13; ++t) s[t] = make_float4(0.f, 0.f, 0.f, 0.f);

    const float* qp = q + (size_t)(b * 2 + g) * hd * HW + hw;
    for (int c = 0; c < hd; ++c) {
        float qv = qp[(size_t)c * HW];
        const float4* kr = (const float4*)(klds + c * 52);
#pragma unroll
        for (int t = 0; t < 13; ++t) {
            float4 kv = kr[t];
            s[t].x += qv * kv.x; s[t].y += qv * kv.y;
            s[t].z += qv * kv.z; s[t].w += qv * kv.w;
        }
    }

    float e[18];
#pragma unroll
    for (int o = 0; o < 18; ++o) {
        const float4* pr = (const float4*)(plds + o * 52);
        float4 a = make_float4(0.f, 0.f, 0.f, 0.f);
#pragma unroll
        for (int t = 0; t < 13; ++t) {
            float4 pv = pr[t];
            a.x += s[t].x * pv.x; a.y += s[t].y * pv.y;
            a.z += s[t].z * pv.z; a.w += s[t].w * pv.w;
        }
        e[o] = pblds[o] + a.x + a.y + a.z + a.w;
    }

    float* outp = attn + (size_t)(b * 2 + g) * 18 * HW + hw;
#pragma unroll
    for (int half = 0; half < 2; ++half) {
        int base = half * 9;
        float m = e[base];
#pragma unroll
        for (int k = 1; k < 9; ++k) m = fmaxf(m, e[base + k]);
        float sum = 0.f, ex[9];
#pragma unroll
        for (int k = 0; k < 9; ++k) { ex[k] = expf(e[base + k] - m); sum += ex[k]; }
        float inv = 1.0f / sum;
#pragma unroll
        for (int k = 0; k < 9; ++k) outp[(size_t)(base + k) * HW] = ex[k] * inv;
    }
}

// ---------------------------------------------------------------------------
// Dynamic depthwise 3x3 mix, tap-major attn layout. grid (49, C, B), block 256.
// ---------------------------------------------------------------------------
__global__ __launch_bounds__(256) void dyndw_k(
    const float* __restrict__ x, const float* __restrict__ attn,
    float* __restrict__ y, int C, int C_half, int hd, size_t x_bstride)
{
    const int b = blockIdx.z, c = blockIdx.y;
    const int hw = blockIdx.x * 256 + threadIdx.x;
    const int h = hw / W_IMG, w = hw - h * W_IMG;

    const int half = c / C_half;
    const int g = (c - half * C_half) / hd;

    const float* ap = attn + ((size_t)(b * 2 + g) * 18 + half * 9) * HW + hw;
    float a[9];
#pragma unroll
    for (int k = 0; k < 9; ++k) a[k] = ap[(size_t)k * HW];

    const float* xp = x + (size_t)b * x_bstride + (size_t)c * HW;
    float s = 0.f;
#pragma unroll
    for (int i = 0; i < 3; ++i) {
        int hh = h + i - 1;
#pragma unroll
        for (int j = 0; j < 3; ++j) {
            int ww = w + j - 1;
            float v = (hh >= 0 && hh < 112 && ww >= 0 && ww < 112)
                          ? xp[hh * W_IMG + ww] : 0.f;
            s += v * a[i * 3 + j];
        }
    }
    y[((size_t)b * C + c) * HW + hw] = s;
}

// ---------------------------------------------------------------------------
extern "C" void kernel_launch(void* const* d_in, const int* in_sizes, int n_in,
                              void* d_out, int out_size, void* d_ws, size_t ws_size,
                              hipStream_t stream) {
    const float* x      = (const float*)d_in[0];
    const float* pin_w  = (const float*)d_in[1];
    const float* ctx_w  = (const float*)d_in[2];
    const float* ctx1_w = (const float*)d_in[3];
    const float* ctx2_w = (const float*)d_in[4];
    const float* pout_w = (const float*)d_in[5];
    const float* cm0_q  = (const float*)d_in[6];
    const float* cm0_k  = (const float*)d_in[7];
    const float* cm0_p  = (const float*)d_in[8];
    const float* cm0_pb = (const float*)d_in[9];
    const float* cm0_o  = (const float*)d_in[10];
    const float* cm1_q  = (const float*)d_in[11];
    const float* cm1_k  = (const float*)d_in[12];
    const float* cm1_p  = (const float*)d_in[13];
    const float* cm1_pb = (const float*)d_in[14];
    const float* cm1_o  = (const float*)d_in[15];
    const float* cm2_q  = (const float*)d_in[16];
    const float* cm2_k  = (const float*)d_in[17];
    const float* cm2_p  = (const float*)d_in[18];
    const float* cm2_pb = (const float*)d_in[19];
    const float* cm2_o  = (const float*)d_in[20];
    float* out = (float*)d_out;

    float* ws = (float*)d_ws;
    // ---- fp32 region (floats) ----
    float* x_in  = ws;                          // [2,344,HW]
    float* x1p   = ws;                          // [2,172,HW] (after x_in dead)
    float* prod  = ws + 4315136;                // [2,172,HW]
    float* y0    = ws + 8630272;                // [2,344,HW]
    float* y1    = ws + 8630272;                // [2,172,HW]
    float* y2    = ws + 12945408;               // [2,172,HW]
    float* x_dw  = ws + 17260544;               // [2,344,HW]
    float* ctxb  = ws + 25890816;               // [2,86,HW]
    float* ctx1  = ws + 28048384;               // [2,43,HW]
    float* ctx2  = ws + 29127168;               // [2,43,HW]
    float* q0    = ws + 30205952;               // [2,172,HW]
    float* q1    = ws + 30205952;               // [2,86,HW] (after q0 dead)
    float* q2    = ws + 32363520;               // [2,86,HW]
    float* attnb = ws + 34521088;               // [2,2,18,HW]
    float* pooled= ws + 35424256;               // [2,86,49]
    float* keyb  = ws + 35432704;               // [2,172,49]
    // ---- bf16 region (ushorts) ----
    unsigned short* ub = (unsigned short*)(ws + 35449568);
    // conv entries: 0 pin | 1 ctx+q0 | 2 cm0_o | 3 ctx1+q1 | 4 ctx2+q2
    //               5 cm1_o | 6 cm2_o | 7 pout   (Mp padded to x32)
    static const int WOFF[8] = {0, 45056, 247808, 495616, 557056, 618496, 692224, 765952};
    static const int WO1[8]  = {344, 86, 344, 43, 43, 172, 172, 64};
    static const int WO[8]   = {344, 258, 344, 129, 129, 172, 172, 64};
    static const int WK[8]   = {64, 344, 344, 172, 172, 172, 172, 172};
    static const int WKP[8]  = {64, 352, 352, 192, 192, 192, 192, 192};
    static const int WMP[8]  = {352, 288, 352, 160, 160, 192, 192, 64};
    // X_t planes
    unsigned short* xt_hi   = ub + 790528;      // [2,HW,64]
    unsigned short* xt_lo   = ub + 2396160;
    unsigned short* xint_hi = ub + 4001792;     // [2,HW,352] (pool A)
    unsigned short* xint_lo = ub + 12832768;
    unsigned short* x1t_hi  = ub + 4001792;     // [2,HW,192] (pool A reuse)
    unsigned short* x1t_lo  = ub + 8818688;
    unsigned short* x2t_hi  = ub + 13635584;
    unsigned short* x2t_lo  = ub + 18452480;
    unsigned short* yt_hi   = ub + 23269376;    // [2,HW,352] (pool B)
    unsigned short* yt_lo   = ub + 32100352;
    unsigned short* y1t_hi  = ub + 23269376;    // [2,HW,192] (pool B reuse)
    unsigned short* y1t_lo  = ub + 28086272;
    unsigned short* y2t_hi  = ub + 32903168;
    unsigned short* y2t_lo  = ub + 37720064;
    unsigned short* pt_hi   = ub + 42536960;    // [2,HW,192]
    unsigned short* pt_lo   = ub + 47353856;

    const float sc0 = 1.0f / sqrtf(86.0f);
    const float sc1 = 1.0f / sqrtf(43.0f);
    const size_t BS344 = (size_t)344 * HW, BS172 = (size_t)172 * HW, BS64 = (size_t)64 * HW;

    // ---- 0. split/concat all weights (q-scales folded into weights) ----
    WSplitArgs wa;
    const float* wsrc1[8] = {pin_w, ctx_w, cm0_o, ctx1_w, ctx2_w, cm1_o, cm2_o, pout_w};
    const float* wsrc2[8] = {nullptr, cm0_q, nullptr, cm1_q, cm2_q, nullptr, nullptr, nullptr};
    const float wsc2[8]   = {1.f, sc0, 1.f, sc1, sc1, 1.f, 1.f, 1.f};
    for (int i = 0; i < 8; ++i) {
        wa.src[i] = wsrc1[i]; wa.src2[i] = wsrc2[i];
        wa.hi[i]  = ub + WOFF[i];
        wa.lo[i]  = ub + WOFF[i] + WMP[i] * WKP[i];
        wa.O1[i] = WO1[i]; wa.O[i] = WO[i]; wa.K[i] = WK[i]; wa.Kp[i] = WKP[i];
        wa.MpKp[i] = WMP[i] * WKP[i];
        wa.scale2[i] = wsc2[i];
    }
    wsplit_k<<<dim3(484, 8), 256, 0, stream>>>(wa);

#define TSPLIT(SRC, BSTR, C, KP, HI, LO)                                        \
    tsplit_k<<<dim3(392, (KP) / 32, B_SZ), 256, 0, stream>>>(SRC, BSTR, C, KP, HI, LO)
#define GEMM(CI, BH, BL, OUTA, OUTB, OB, MODE, RES, RB, MUL, MB)                \
    gemm_k<<<dim3((WMP[CI] / 32) * 56, B_SZ), 256, 0, stream>>>(                \
        BH, BL, ub + WOFF[CI], ub + WOFF[CI] + WMP[CI] * WKP[CI],               \
        WKP[CI], WMP[CI] / 32, OUTA, WO1[CI], OUTB, OB, MODE, RES, RB, MUL, MB)

    // ---- pin: x_in = pin_w @ x ----
    TSPLIT(x, BS64, 64, 64, xt_hi, xt_lo);
    GEMM(0, xt_hi, xt_lo, x_in, nullptr, 0, 0, nullptr, 0, nullptr, 0);
    TSPLIT(x_in, BS344, 344, 352, xint_hi, xint_lo);

    // ---- contmix0: fused ctx_dw + q0 GEMM ----
    GEMM(1, xint_hi, xint_lo, ctxb, q0, 172, 0, nullptr, 0, nullptr, 0);
    pool_k<<<dim3(86, B_SZ), dim3(64), 0, stream>>>(ctxb, pooled, 86);
    keygemm_k<<<dim3(172, B_SZ), dim3(64), 0, stream>>>(pooled, cm0_k, keyb, 86, 172);
    attn_k<<<dim3(49, 2, B_SZ), dim3(256), 0, stream>>>(q0, keyb, cm0_p, cm0_pb, attnb, 86);
    dyndw_k<<<dim3(49, 344, B_SZ), dim3(256), 0, stream>>>(x_in, attnb, y0, 344, 172, 86, BS344);
    TSPLIT(y0, BS344, 344, 352, yt_hi, yt_lo);
    GEMM(2, yt_hi, yt_lo, x_dw, nullptr, 0, 0, nullptr, 0, nullptr, 0);

    // ---- transpose halves of x_dw ----
    TSPLIT(x_dw, BS344, 172, 192, x1t_hi, x1t_lo);
    TSPLIT(x_dw + BS172, BS344, 172, 192, x2t_hi, x2t_lo);

    // ---- contmix1 on x1 ----
    GEMM(3, x1t_hi, x1t_lo, ctx1, q1, 86, 0, nullptr, 0, nullptr, 0);
    pool_k<<<dim3(43, B_SZ), dim3(64), 0, stream>>>(ctx1, pooled, 43);
    keygemm_k<<<dim3(86, B_SZ), dim3(64), 0, stream>>>(pooled, cm1_k, keyb, 43, 86);
    attn_k<<<dim3(49, 2, B_SZ), dim3(256), 0, stream>>>(q1, keyb, cm1_p, cm1_pb, attnb, 43);
    dyndw_k<<<dim3(49, 172, B_SZ), dim3(256), 0, stream>>>(x_dw, attnb, y1, 172, 86, 43, BS344);
    TSPLIT(y1, BS172, 172, 192, y1t_hi, y1t_lo);
    GEMM(5, y1t_hi, y1t_lo, x1p, nullptr, 0, 2, x_dw, BS344, nullptr, 0);

    // ---- contmix2 on x2 ----
    GEMM(4, x2t_hi, x2t_lo, ctx2, q2, 86, 0, nullptr, 0, nullptr, 0);
    pool_k<<<dim3(43, B_SZ), dim3(64), 0, stream>>>(ctx2, pooled, 43);
    keygemm_k<<<dim3(86, B_SZ), dim3(64), 0, stream>>>(pooled, cm2_k, keyb, 43, 86);
    attn_k<<<dim3(49, 2, B_SZ), dim3(256), 0, stream>>>(q2, keyb, cm2_p, cm2_pb, attnb, 43);
    dyndw_k<<<dim3(49, 172, B_SZ), dim3(256), 0, stream>>>(x_dw + BS172, attnb, y2, 172, 86, 43, BS344);
    TSPLIT(y2, BS172, 172, 192, y2t_hi, y2t_lo);
    GEMM(6, y2t_hi, y2t_lo, prod, nullptr, 0, 3, x_dw + BS172, BS344, x1p, BS172);

    // ---- pout ----
    TSPLIT(prod, BS172, 172, 192, pt_hi, pt_lo);
    GEMM(7, pt_hi, pt_lo, out, nullptr, 0, 0, nullptr, 0, nullptr, 0);

#undef TSPLIT
#undef GEMM
}